// Round 1
// baseline (392.610 us; speedup 1.0000x reference)
//
#include <hip/hip_runtime.h>

// Sparse (local + vertical-stride) causal attention, MI355X gfx950.
// B=1, S=2048, H=32, D=128, BLOCK=64, LOCAL=16, VERT=8, SLIDE=1, OFFSET=0.
// Flash-style online softmax, bf16 MFMA (16x16x32), fp32 accumulation.

#define S_LEN 2048
#define NH    32
#define HD    128
#define BLK   64
#define LOCALB 16
#define VERTS  8

typedef __attribute__((ext_vector_type(8))) short short8;
typedef __attribute__((ext_vector_type(4))) float f32x4;

__device__ __forceinline__ unsigned short f2bf(float f) {
    union { float f; unsigned u; } x; x.f = f;
    unsigned r = x.u + 0x7FFFu + ((x.u >> 16) & 1u);  // RNE
    return (unsigned short)(r >> 16);
}

__global__ __launch_bounds__(256)
void sparse_attn_kernel(const float* __restrict__ Q,
                        const float* __restrict__ K,
                        const float* __restrict__ V,
                        float* __restrict__ O)
{
    const int qb   = blockIdx.x;   // q block 0..31
    const int h    = blockIdx.y;   // head 0..31
    const int tid  = threadIdx.x;  // 0..255
    const int wave = tid >> 6;     // 0..3, owns q rows [wave*16, wave*16+16)
    const int lane = tid & 63;
    const int m16  = lane & 15;    // MFMA m/n index
    const int quad = lane >> 4;    // 0..3

    // LDS: row strides padded to keep 16B alignment and break bank aliasing.
    __shared__ __align__(16) unsigned short Ks[64][136];   // [key][d]
    __shared__ __align__(16) unsigned short Vt[128][72];   // [d][key]
    __shared__ __align__(16) unsigned short Ps[64][72];    // [q_local][key]

    // ---- Load Q fragments once (A-operand layout: A[m=lane&15][k=quad*8+j]) ----
    short8 qf[4];
    {
        const int qrow = qb * 64 + wave * 16 + m16;
        const float* qp = Q + ((size_t)qrow * NH + h) * HD + quad * 8;
        #pragma unroll
        for (int ks = 0; ks < 4; ++ks) {
            short8 a;
            #pragma unroll
            for (int j = 0; j < 8; ++j) a[j] = (short)f2bf(qp[ks * 32 + j]);
            qf[ks] = a;
        }
    }

    // Output accumulator: 8 d-tiles of 16x16, C layout (row = quad*4+reg).
    f32x4 acc[8];
    #pragma unroll
    for (int dt = 0; dt < 8; ++dt) { acc[dt][0]=0.f; acc[dt][1]=0.f; acc[dt][2]=0.f; acc[dt][3]=0.f; }
    float mrow[4] = { -3.0e38f, -3.0e38f, -3.0e38f, -3.0e38f };
    float lrow[4] = { 0.f, 0.f, 0.f, 0.f };

    const float scale = 0.08838834764831845f;   // 1/sqrt(128)
    const float LOG2E = 1.44269504088896f;

    for (int kb = 0; kb <= qb; ++kb) {
        const bool localb = (qb - kb) < LOCALB;
        const bool vertb  = ((kb + h + 1) % VERTS) == 0;
        if (!(localb || vertb)) continue;

        __syncthreads();   // protect LDS from previous iteration's readers

        // ---- Stage K (row-major) and V (transposed) fp32 -> bf16 ----
        for (int i = tid; i < 2048; i += 256) {
            const int key = i >> 5;            // 0..63
            const int d4  = (i & 31) << 2;     // 0,4,...,124
            const size_t base = ((size_t)(kb * 64 + key) * NH + h) * HD + d4;
            const float4 kv = *reinterpret_cast<const float4*>(K + base);
            const float4 vv = *reinterpret_cast<const float4*>(V + base);
            Ks[key][d4 + 0] = f2bf(kv.x);
            Ks[key][d4 + 1] = f2bf(kv.y);
            Ks[key][d4 + 2] = f2bf(kv.z);
            Ks[key][d4 + 3] = f2bf(kv.w);
            Vt[d4 + 0][key] = f2bf(vv.x);
            Vt[d4 + 1][key] = f2bf(vv.y);
            Vt[d4 + 2][key] = f2bf(vv.z);
            Vt[d4 + 3][key] = f2bf(vv.w);
        }
        __syncthreads();

        // ---- S = Q K^T (16 rows x 64 cols per wave) ----
        f32x4 sc[4];
        #pragma unroll
        for (int nt = 0; nt < 4; ++nt) {
            f32x4 s; s[0]=0.f; s[1]=0.f; s[2]=0.f; s[3]=0.f;
            #pragma unroll
            for (int ks = 0; ks < 4; ++ks) {
                const short8 b = *reinterpret_cast<const short8*>(&Ks[nt * 16 + m16][ks * 32 + quad * 8]);
                s = __builtin_amdgcn_mfma_f32_16x16x32_bf16(qf[ks], b, s, 0, 0, 0);
            }
            sc[nt] = s;
        }

        // ---- scale + diagonal causal mask + online softmax ----
        #pragma unroll
        for (int nt = 0; nt < 4; ++nt) {
            #pragma unroll
            for (int r = 0; r < 4; ++r) sc[nt][r] *= scale;
        }
        if (kb == qb) {
            #pragma unroll
            for (int nt = 0; nt < 4; ++nt) {
                const int col = nt * 16 + m16;
                #pragma unroll
                for (int r = 0; r < 4; ++r) {
                    const int row = wave * 16 + quad * 4 + r;
                    if (col > row) sc[nt][r] = -1.0e30f;
                }
            }
        }

        #pragma unroll
        for (int r = 0; r < 4; ++r) {
            float vmax = fmaxf(fmaxf(sc[0][r], sc[1][r]), fmaxf(sc[2][r], sc[3][r]));
            #pragma unroll
            for (int off = 1; off < 16; off <<= 1) vmax = fmaxf(vmax, __shfl_xor(vmax, off));
            const float mnew = fmaxf(mrow[r], vmax);
            const float alpha = __builtin_exp2f((mrow[r] - mnew) * LOG2E);
            lrow[r] *= alpha;
            #pragma unroll
            for (int dt = 0; dt < 8; ++dt) acc[dt][r] *= alpha;
            float rs = 0.f;
            #pragma unroll
            for (int nt = 0; nt < 4; ++nt) {
                const float p = __builtin_exp2f((sc[nt][r] - mnew) * LOG2E);
                sc[nt][r] = p;
                rs += p;
            }
            #pragma unroll
            for (int off = 1; off < 16; off <<= 1) rs += __shfl_xor(rs, off);
            lrow[r] += rs;
            mrow[r] = mnew;
        }

        // ---- P: C layout -> LDS (so PV can read A-operand layout) ----
        #pragma unroll
        for (int nt = 0; nt < 4; ++nt) {
            const int col = nt * 16 + m16;
            #pragma unroll
            for (int r = 0; r < 4; ++r) {
                Ps[wave * 16 + quad * 4 + r][col] = f2bf(sc[nt][r]);
            }
        }
        __syncthreads();

        // ---- O += P V ----
        short8 af[2];
        #pragma unroll
        for (int k2 = 0; k2 < 2; ++k2)
            af[k2] = *reinterpret_cast<const short8*>(&Ps[wave * 16 + m16][k2 * 32 + quad * 8]);
        #pragma unroll
        for (int dt = 0; dt < 8; ++dt) {
            #pragma unroll
            for (int k2 = 0; k2 < 2; ++k2) {
                const short8 b = *reinterpret_cast<const short8*>(&Vt[dt * 16 + m16][k2 * 32 + quad * 8]);
                acc[dt] = __builtin_amdgcn_mfma_f32_16x16x32_bf16(af[k2], b, acc[dt], 0, 0, 0);
            }
        }
    }

    // ---- Epilogue: divide by l, store fp32 ----
    #pragma unroll
    for (int r = 0; r < 4; ++r) {
        const float inv = 1.0f / lrow[r];
        const int qrow = qb * 64 + wave * 16 + quad * 4 + r;
        #pragma unroll
        for (int dt = 0; dt < 8; ++dt) {
            O[((size_t)qrow * NH + h) * HD + dt * 16 + m16] = acc[dt][r] * inv;
        }
    }
}

extern "C" void kernel_launch(void* const* d_in, const int* in_sizes, int n_in,
                              void* d_out, int out_size, void* d_ws, size_t ws_size,
                              hipStream_t stream) {
    const float* q = (const float*)d_in[0];
    const float* k = (const float*)d_in[1];
    const float* v = (const float*)d_in[2];
    float* out = (float*)d_out;
    dim3 grid(S_LEN / BLK, NH);   // (32 q-blocks, 32 heads)
    dim3 block(256);
    sparse_attn_kernel<<<grid, block, 0, stream>>>(q, k, v, out);
}

// Round 2
// 293.467 us; speedup vs baseline: 1.3378x; 1.3378x over previous
//
#include <hip/hip_runtime.h>

// Sparse (local + vertical-stride) causal attention, MI355X gfx950.
// B=1, S=2048, H=32, D=128, BLOCK=64, LOCAL=16, VERT=8, SLIDE=1, OFFSET=0.
// Flash-style online softmax, bf16 MFMA (16x16x32), fp32 accumulation.
// R2: conflict-free-ish staging (pair-packed b32 V/P stores), LPT+XCD grid.

#define S_LEN 2048
#define NH    32
#define HD    128
#define BLK   64
#define LOCALB 16
#define VERTS  8

typedef __attribute__((ext_vector_type(8))) short short8;
typedef __attribute__((ext_vector_type(4))) float f32x4;

__device__ __forceinline__ unsigned f2bf_u(float f) {
    union { float f; unsigned u; } x; x.f = f;
    return x.u;
}
// pack bf16(a) into low16, bf16(b) into high16 (round-half-up; err budget huge)
__device__ __forceinline__ unsigned bfpk(float a, float b) {
    return ((f2bf_u(a) + 0x8000u) >> 16) | ((f2bf_u(b) + 0x8000u) & 0xFFFF0000u);
}
__device__ __forceinline__ unsigned short f2bf(float f) {
    return (unsigned short)((f2bf_u(f) + 0x8000u) >> 16);
}

__global__ __launch_bounds__(256)
void sparse_attn_kernel(const float* __restrict__ Q,
                        const float* __restrict__ K,
                        const float* __restrict__ V,
                        float* __restrict__ O)
{
    // LPT order (heavy qb first) + XCD head clustering (id%8 -> 4 heads/XCD)
    const int id   = blockIdx.x;
    const int xcd  = id & 7;
    const int slot = id >> 3;            // 0..127
    const int h    = xcd * 4 + (slot & 3);
    const int qb   = 31 - (slot >> 2);

    const int tid  = threadIdx.x;
    const int wave = tid >> 6;
    const int lane = tid & 63;
    const int m16  = lane & 15;
    const int quad = lane >> 4;

    __shared__ __align__(16) unsigned short Ks[64][136];   // [key][d]
    __shared__ __align__(16) unsigned int   Vp[128][36];   // [d][key-pair] bf16x2
    __shared__ __align__(16) unsigned int   Pp[64][36];    // [q_local][key-pair] bf16x2

    // ---- Q fragments (A layout: A[m=m16][k=quad*8+j]), float4 loads ----
    short8 qf[4];
    {
        const int qrow = qb * 64 + wave * 16 + m16;
        const float* qp = Q + ((size_t)qrow * NH + h) * HD + quad * 8;
        #pragma unroll
        for (int ks = 0; ks < 4; ++ks) {
            const float4 a = *reinterpret_cast<const float4*>(qp + ks * 32);
            const float4 b = *reinterpret_cast<const float4*>(qp + ks * 32 + 4);
            short8 f;
            f[0]=(short)f2bf(a.x); f[1]=(short)f2bf(a.y); f[2]=(short)f2bf(a.z); f[3]=(short)f2bf(a.w);
            f[4]=(short)f2bf(b.x); f[5]=(short)f2bf(b.y); f[6]=(short)f2bf(b.z); f[7]=(short)f2bf(b.w);
            qf[ks] = f;
        }
    }

    f32x4 acc[8];
    #pragma unroll
    for (int dt = 0; dt < 8; ++dt) { acc[dt][0]=0.f; acc[dt][1]=0.f; acc[dt][2]=0.f; acc[dt][3]=0.f; }
    float mrow[4] = { -3.0e38f, -3.0e38f, -3.0e38f, -3.0e38f };
    float lrow[4] = { 0.f, 0.f, 0.f, 0.f };

    const float scale = 0.08838834764831845f;   // 1/sqrt(128)
    const float LOG2E = 1.44269504088896f;

    for (int kb = 0; kb <= qb; ++kb) {
        const bool localb = (qb - kb) < LOCALB;
        const bool vertb  = ((kb + h + 1) % VERTS) == 0;
        if (!(localb || vertb)) continue;

        __syncthreads();   // previous iteration's LDS readers done

        // ---- Stage K: contiguous b64 stores, conflict-free ----
        #pragma unroll
        for (int it = 0; it < 8; ++it) {
            const int i   = it * 256 + tid;
            const int key = i >> 5;
            const int d4  = (i & 31) << 2;
            const float4 kv = *reinterpret_cast<const float4*>(
                K + ((size_t)(kb * 64 + key) * NH + h) * HD + d4);
            uint2 pk; pk.x = bfpk(kv.x, kv.y); pk.y = bfpk(kv.z, kv.w);
            *reinterpret_cast<uint2*>(&Ks[key][d4]) = pk;
        }

        // ---- Stage V transposed: pair-pack keys via shfl_xor(1), b32 stores ----
        #pragma unroll
        for (int it = 0; it < 8; ++it) {
            const int kgroup = (it & 1) * 4 + wave;          // 0..7
            const int dg     = it >> 1;                      // 0..3
            const int key    = kgroup * 8 + (lane & 7);      // 0..63
            const int d4     = dg * 32 + (lane >> 3) * 4;    // 0..124
            const float4 vv = *reinterpret_cast<const float4*>(
                V + ((size_t)(kb * 64 + key) * NH + h) * HD + d4);
            const unsigned p0 = bfpk(vv.x, vv.y);            // d4+0 | d4+1<<16 (my key)
            const unsigned p1 = bfpk(vv.z, vv.w);            // d4+2 | d4+3<<16
            const unsigned q0 = __shfl_xor(p0, 1);           // partner key
            const unsigned q1 = __shfl_xor(p1, 1);
            const int c = kgroup * 4 + ((lane & 7) >> 1);    // key-pair column
            if ((lane & 1) == 0) {  // even key: rows d4+0, d4+1; low=mine, high=partner
                Vp[d4 + 0][c] = (p0 & 0xFFFFu) | (q0 << 16);
                Vp[d4 + 1][c] = (p0 >> 16)     | (q0 & 0xFFFF0000u);
            } else {                // odd key: rows d4+2, d4+3; low=partner, high=mine
                Vp[d4 + 2][c] = (q1 & 0xFFFFu) | (p1 << 16);
                Vp[d4 + 3][c] = (q1 >> 16)     | (p1 & 0xFFFF0000u);
            }
        }
        __syncthreads();

        // ---- S = Q K^T ----
        f32x4 sc[4];
        #pragma unroll
        for (int nt = 0; nt < 4; ++nt) {
            f32x4 s; s[0]=0.f; s[1]=0.f; s[2]=0.f; s[3]=0.f;
            #pragma unroll
            for (int ks = 0; ks < 4; ++ks) {
                const short8 b = *reinterpret_cast<const short8*>(&Ks[nt * 16 + m16][ks * 32 + quad * 8]);
                s = __builtin_amdgcn_mfma_f32_16x16x32_bf16(qf[ks], b, s, 0, 0, 0);
            }
            sc[nt] = s;
        }

        // ---- scale + diagonal mask + online softmax ----
        #pragma unroll
        for (int nt = 0; nt < 4; ++nt) {
            #pragma unroll
            for (int r = 0; r < 4; ++r) sc[nt][r] *= scale;
        }
        if (kb == qb) {
            #pragma unroll
            for (int nt = 0; nt < 4; ++nt) {
                const int col = nt * 16 + m16;
                #pragma unroll
                for (int r = 0; r < 4; ++r) {
                    const int row = wave * 16 + quad * 4 + r;
                    if (col > row) sc[nt][r] = -1.0e30f;
                }
            }
        }

        #pragma unroll
        for (int r = 0; r < 4; ++r) {
            float vmax = fmaxf(fmaxf(sc[0][r], sc[1][r]), fmaxf(sc[2][r], sc[3][r]));
            #pragma unroll
            for (int off = 1; off < 16; off <<= 1) vmax = fmaxf(vmax, __shfl_xor(vmax, off));
            const float mnew = fmaxf(mrow[r], vmax);
            const float alpha = __builtin_exp2f((mrow[r] - mnew) * LOG2E);
            lrow[r] *= alpha;
            #pragma unroll
            for (int dt = 0; dt < 8; ++dt) acc[dt][r] *= alpha;
            float rs = 0.f;
            #pragma unroll
            for (int nt = 0; nt < 4; ++nt) {
                const float p = __builtin_exp2f((sc[nt][r] - mnew) * LOG2E);
                sc[nt][r] = p;
                rs += p;
            }
            #pragma unroll
            for (int off = 1; off < 16; off <<= 1) rs += __shfl_xor(rs, off);
            lrow[r] += rs;
            mrow[r] = mnew;
        }

        // ---- P -> LDS, pair-packed b32 (cols m16,m16^1), 2-way free ----
        {
            const int colw = (4 * 16 * 0 + 0, (0)); (void)colw;
        }
        #pragma unroll
        for (int nt = 0; nt < 4; ++nt) {
            const float o0 = __shfl_xor(sc[nt][0], 1);
            const float o1 = __shfl_xor(sc[nt][1], 1);
            const float o2 = __shfl_xor(sc[nt][2], 1);
            const float o3 = __shfl_xor(sc[nt][3], 1);
            const int cw = (nt * 16 + (m16 & ~1)) >> 1;      // dword col
            const int rbase = wave * 16 + quad * 4;
            if ((m16 & 1) == 0) {   // even col lane: rows +0, +1
                Pp[rbase + 0][cw] = bfpk(sc[nt][0], o0);
                Pp[rbase + 1][cw] = bfpk(sc[nt][1], o1);
            } else {                // odd col lane: rows +2, +3 (low = partner/even col)
                Pp[rbase + 2][cw] = bfpk(o2, sc[nt][2]);
                Pp[rbase + 3][cw] = bfpk(o3, sc[nt][3]);
            }
        }
        __syncthreads();

        // ---- O += P V ----
        short8 af[2];
        #pragma unroll
        for (int k2 = 0; k2 < 2; ++k2) {
            const unsigned short* prow = reinterpret_cast<const unsigned short*>(&Pp[wave * 16 + m16][0]);
            af[k2] = *reinterpret_cast<const short8*>(prow + k2 * 32 + quad * 8);
        }
        #pragma unroll
        for (int dt = 0; dt < 8; ++dt) {
            #pragma unroll
            for (int k2 = 0; k2 < 2; ++k2) {
                const unsigned short* vrow = reinterpret_cast<const unsigned short*>(&Vp[dt * 16 + m16][0]);
                const short8 b = *reinterpret_cast<const short8*>(vrow + k2 * 32 + quad * 8);
                acc[dt] = __builtin_amdgcn_mfma_f32_16x16x32_bf16(af[k2], b, acc[dt], 0, 0, 0);
            }
        }
    }

    // ---- Epilogue ----
    #pragma unroll
    for (int r = 0; r < 4; ++r) {
        const float inv = 1.0f / lrow[r];
        const int qrow = qb * 64 + wave * 16 + quad * 4 + r;
        #pragma unroll
        for (int dt = 0; dt < 8; ++dt) {
            O[((size_t)qrow * NH + h) * HD + dt * 16 + m16] = acc[dt][r] * inv;
        }
    }
}

extern "C" void kernel_launch(void* const* d_in, const int* in_sizes, int n_in,
                              void* d_out, int out_size, void* d_ws, size_t ws_size,
                              hipStream_t stream) {
    const float* q = (const float*)d_in[0];
    const float* k = (const float*)d_in[1];
    const float* v = (const float*)d_in[2];
    float* out = (float*)d_out;
    dim3 grid(1024);
    dim3 block(256);
    sparse_attn_kernel<<<grid, block, 0, stream>>>(q, k, v, out);
}

// Round 3
// 235.081 us; speedup vs baseline: 1.6701x; 1.2484x over previous
//
#include <hip/hip_runtime.h>

// Sparse (local + vertical-stride) causal attention, MI355X gfx950.
// B=1, S=2048, H=32, D=128, BLOCK=64, LOCAL=16, VERT=8, SLIDE=1, OFFSET=0.
// R3: register prefetch of next k-block + lgkm-only raw barriers (no vmcnt
// drain), scale*log2e folded into Q frags, row-sum l via ones-MFMA.

#define NH    32
#define HD    128
#define LOCALB 16

typedef __attribute__((ext_vector_type(8))) short short8;
typedef __attribute__((ext_vector_type(4))) float f32x4;

static __device__ __forceinline__ unsigned f2u(float f) {
    union { float f; unsigned u; } x; x.f = f; return x.u;
}
static __device__ __forceinline__ unsigned bfpk(float a, float b) {
    return ((f2u(a) + 0x8000u) >> 16) | ((f2u(b) + 0x8000u) & 0xFFFF0000u);
}
static __device__ __forceinline__ unsigned short f2bf(float f) {
    return (unsigned short)((f2u(f) + 0x8000u) >> 16);
}

// Workgroup barrier that waits ONLY on LDS ops (lgkmcnt). Global prefetch
// loads stay in flight across it; their vmcnt waits are dependency-driven
// at the point of register consumption (next iteration's staging).
static __device__ __forceinline__ void wg_barrier() {
    asm volatile("" ::: "memory");
    __builtin_amdgcn_s_waitcnt(0xC07F);   // vmcnt(63) expcnt(7) lgkmcnt(0)
    __builtin_amdgcn_s_barrier();
    asm volatile("" ::: "memory");
}

static __device__ __forceinline__ bool blk_active(int qb, int kb, int h) {
    return ((qb - kb) < LOCALB) || (((kb + h + 1) & 7) == 0);
}

__global__ __launch_bounds__(256)
void sparse_attn_kernel(const float* __restrict__ Q,
                        const float* __restrict__ K,
                        const float* __restrict__ V,
                        float* __restrict__ O)
{
    // LPT (heavy qb first) + XCD head clustering
    const int id   = blockIdx.x;
    const int h    = (id & 7) * 4 + ((id >> 3) & 3);
    const int qb   = 31 - (id >> 5);

    const int tid  = threadIdx.x;
    const int wave = tid >> 6;
    const int lane = tid & 63;
    const int m16  = lane & 15;
    const int quad = lane >> 4;

    __shared__ __align__(16) unsigned short Ks[64][136];   // [key][d]
    __shared__ __align__(16) unsigned int   Vp[128][36];   // [d][key-pair] bf16x2
    __shared__ __align__(16) unsigned int   Pp[64][36];    // [q_local][key-pair] bf16x2

    // ---- Q fragments, scale*log2e folded in ----
    const float QSC = 0.08838834764831845f * 1.44269504088896f;
    short8 qf[4];
    {
        const int qrow = qb * 64 + wave * 16 + m16;
        const float* qp = Q + ((size_t)qrow * NH + h) * HD + quad * 8;
        #pragma unroll
        for (int ks = 0; ks < 4; ++ks) {
            const float4 a = *reinterpret_cast<const float4*>(qp + ks * 32);
            const float4 b = *reinterpret_cast<const float4*>(qp + ks * 32 + 4);
            short8 f;
            f[0]=(short)f2bf(a.x*QSC); f[1]=(short)f2bf(a.y*QSC);
            f[2]=(short)f2bf(a.z*QSC); f[3]=(short)f2bf(a.w*QSC);
            f[4]=(short)f2bf(b.x*QSC); f[5]=(short)f2bf(b.y*QSC);
            f[6]=(short)f2bf(b.z*QSC); f[7]=(short)f2bf(b.w*QSC);
            qf[ks] = f;
        }
    }

    f32x4 acc[8];
    #pragma unroll
    for (int dt = 0; dt < 8; ++dt) { acc[dt][0]=0.f; acc[dt][1]=0.f; acc[dt][2]=0.f; acc[dt][3]=0.f; }
    f32x4 accl = {0.f, 0.f, 0.f, 0.f};                 // row-sums via ones-MFMA
    float mrow[4] = { -3.0e38f, -3.0e38f, -3.0e38f, -3.0e38f };

    short8 ones;
    #pragma unroll
    for (int j = 0; j < 8; ++j) ones[j] = (short)0x3F80;   // bf16 1.0

    // per-thread staging coordinates (constant)
    const int kkey0 = tid >> 5;            // + it*8
    const int kd4   = (tid & 31) << 2;
    const int vkey0 = wave * 8 + (lane & 7);   // + (it&1)*32
    const int vd40  = (lane >> 3) << 2;        // + (it>>1)*32
    const int vc    = wave * 4 + ((lane & 7) >> 1);  // + (it&1)*16

    // ---- prologue: first active block + prefetch ----
    int kb = 0;
    while (!blk_active(qb, kb, h)) ++kb;    // kb<=qb always (diag active)

    float4 kreg[8], vreg[8];
    {
        const float* kp = K + (size_t)kb * 262144 + (size_t)kkey0 * 4096 + h * 128 + kd4;
        #pragma unroll
        for (int it = 0; it < 8; ++it)
            kreg[it] = *reinterpret_cast<const float4*>(kp + it * 32768);
        const float* vp = V + (size_t)kb * 262144 + (size_t)vkey0 * 4096 + h * 128 + vd40;
        #pragma unroll
        for (int it = 0; it < 8; ++it)
            vreg[it] = *reinterpret_cast<const float4*>(vp + (it & 1) * 131072 + (it >> 1) * 32);
    }

    while (kb <= qb) {
        int nkb = kb + 1;
        while (nkb <= qb && !blk_active(qb, nkb, h)) ++nkb;

        wg_barrier();   // prior iteration's LDS reads complete (lgkm only)

        // ---- stage K from regs, then immediately re-issue K prefetch ----
        #pragma unroll
        for (int it = 0; it < 8; ++it) {
            const float4 kv = kreg[it];
            uint2 pk; pk.x = bfpk(kv.x, kv.y); pk.y = bfpk(kv.z, kv.w);
            *reinterpret_cast<uint2*>(&Ks[it * 8 + kkey0][kd4]) = pk;
        }
        if (nkb <= qb) {
            const float* kp = K + (size_t)nkb * 262144 + (size_t)kkey0 * 4096 + h * 128 + kd4;
            #pragma unroll
            for (int it = 0; it < 8; ++it)
                kreg[it] = *reinterpret_cast<const float4*>(kp + it * 32768);
        }

        // ---- stage V transposed (pair-packed b32), then V prefetch ----
        #pragma unroll
        for (int it = 0; it < 8; ++it) {
            const int d4 = (it >> 1) * 32 + vd40;
            const float4 vv = vreg[it];
            const unsigned p0 = bfpk(vv.x, vv.y);
            const unsigned p1 = bfpk(vv.z, vv.w);
            const unsigned q0 = __shfl_xor(p0, 1);
            const unsigned q1 = __shfl_xor(p1, 1);
            const int c = (it & 1) * 16 + vc;
            if ((lane & 1) == 0) {
                Vp[d4 + 0][c] = (p0 & 0xFFFFu) | (q0 << 16);
                Vp[d4 + 1][c] = (p0 >> 16)     | (q0 & 0xFFFF0000u);
            } else {
                Vp[d4 + 2][c] = (q1 & 0xFFFFu) | (p1 << 16);
                Vp[d4 + 3][c] = (q1 >> 16)     | (p1 & 0xFFFF0000u);
            }
        }
        if (nkb <= qb) {
            const float* vp = V + (size_t)nkb * 262144 + (size_t)vkey0 * 4096 + h * 128 + vd40;
            #pragma unroll
            for (int it = 0; it < 8; ++it)
                vreg[it] = *reinterpret_cast<const float4*>(vp + (it & 1) * 131072 + (it >> 1) * 32);
        }

        wg_barrier();   // staging visible

        // ---- S = Q K^T (already in log2 domain) ----
        f32x4 sc[4];
        #pragma unroll
        for (int nt = 0; nt < 4; ++nt) {
            f32x4 s = {0.f, 0.f, 0.f, 0.f};
            #pragma unroll
            for (int ks = 0; ks < 4; ++ks) {
                const short8 b = *reinterpret_cast<const short8*>(&Ks[nt * 16 + m16][ks * 32 + quad * 8]);
                s = __builtin_amdgcn_mfma_f32_16x16x32_bf16(qf[ks], b, s, 0, 0, 0);
            }
            sc[nt] = s;
        }

        // ---- diagonal causal mask ----
        if (kb == qb) {
            #pragma unroll
            for (int nt = 0; nt < 4; ++nt) {
                const int col = nt * 16 + m16;
                #pragma unroll
                for (int r = 0; r < 4; ++r) {
                    const int row = wave * 16 + quad * 4 + r;
                    if (col > row) sc[nt][r] = -1.0e30f;
                }
            }
        }

        // ---- online softmax (exp2 domain); l comes from ones-MFMA later ----
        #pragma unroll
        for (int r = 0; r < 4; ++r) {
            float vmax = fmaxf(fmaxf(sc[0][r], sc[1][r]), fmaxf(sc[2][r], sc[3][r]));
            #pragma unroll
            for (int off = 1; off < 16; off <<= 1) vmax = fmaxf(vmax, __shfl_xor(vmax, off));
            const float mnew = fmaxf(mrow[r], vmax);
            const float alpha = __builtin_exp2f(mrow[r] - mnew);
            accl[r] *= alpha;
            #pragma unroll
            for (int dt = 0; dt < 8; ++dt) acc[dt][r] *= alpha;
            #pragma unroll
            for (int nt = 0; nt < 4; ++nt) sc[nt][r] = __builtin_exp2f(sc[nt][r] - mnew);
            mrow[r] = mnew;
        }

        // ---- P -> LDS, pair-packed b32 ----
        #pragma unroll
        for (int nt = 0; nt < 4; ++nt) {
            const float o0 = __shfl_xor(sc[nt][0], 1);
            const float o1 = __shfl_xor(sc[nt][1], 1);
            const float o2 = __shfl_xor(sc[nt][2], 1);
            const float o3 = __shfl_xor(sc[nt][3], 1);
            const int cw = (nt * 16 + (m16 & ~1)) >> 1;
            const int rbase = wave * 16 + quad * 4;
            if ((m16 & 1) == 0) {
                Pp[rbase + 0][cw] = bfpk(sc[nt][0], o0);
                Pp[rbase + 1][cw] = bfpk(sc[nt][1], o1);
            } else {
                Pp[rbase + 2][cw] = bfpk(o2, sc[nt][2]);
                Pp[rbase + 3][cw] = bfpk(o3, sc[nt][3]);
            }
        }

        wg_barrier();   // P visible

        // ---- O += P V; l += P * 1 ----
        short8 af[2];
        #pragma unroll
        for (int k2 = 0; k2 < 2; ++k2) {
            const unsigned short* prow = reinterpret_cast<const unsigned short*>(&Pp[wave * 16 + m16][0]);
            af[k2] = *reinterpret_cast<const short8*>(prow + k2 * 32 + quad * 8);
        }
        #pragma unroll
        for (int k2 = 0; k2 < 2; ++k2)
            accl = __builtin_amdgcn_mfma_f32_16x16x32_bf16(af[k2], ones, accl, 0, 0, 0);
        #pragma unroll
        for (int dt = 0; dt < 8; ++dt) {
            #pragma unroll
            for (int k2 = 0; k2 < 2; ++k2) {
                const unsigned short* vrow = reinterpret_cast<const unsigned short*>(&Vp[dt * 16 + m16][0]);
                const short8 b = *reinterpret_cast<const short8*>(vrow + k2 * 32 + quad * 8);
                acc[dt] = __builtin_amdgcn_mfma_f32_16x16x32_bf16(af[k2], b, acc[dt], 0, 0, 0);
            }
        }

        kb = nkb;
    }

    // ---- epilogue ----
    #pragma unroll
    for (int r = 0; r < 4; ++r) {
        const float inv = 1.0f / accl[r];
        const int qrow = qb * 64 + wave * 16 + quad * 4 + r;
        #pragma unroll
        for (int dt = 0; dt < 8; ++dt) {
            O[((size_t)qrow * NH + h) * HD + dt * 16 + m16] = acc[dt][r] * inv;
        }
    }
}

extern "C" void kernel_launch(void* const* d_in, const int* in_sizes, int n_in,
                              void* d_out, int out_size, void* d_ws, size_t ws_size,
                              hipStream_t stream) {
    const float* q = (const float*)d_in[0];
    const float* k = (const float*)d_in[1];
    const float* v = (const float*)d_in[2];
    float* out = (float*)d_out;
    sparse_attn_kernel<<<dim3(1024), dim3(256), 0, stream>>>(q, k, v, out);
}

// Round 6
// 208.107 us; speedup vs baseline: 1.8866x; 1.1296x over previous
//
#include <hip/hip_runtime.h>

// Sparse (local + vertical-stride) causal attention, MI355X gfx950.
// B=1, S=2048, H=32, D=128, BLOCK=64, LOCAL=16, VERT=8, SLIDE=1, OFFSET=0.
// R6 == R5 structure: transposed MFMA (S^T = K Q^T, O^T = V^T P^T) with
// PERMUTED K rows in LDS so S^T's C-layout == 16x16x32 B-operand layout ->
// P stays in registers, lane-local softmax (2 shuffles/iter), 2 lgkm-only
// barriers/iter. Epilogue barriers are full __syncthreads() (LDS aliasing
// safety — once per block, negligible).

#define NH 32
#define HD 128
#define LOCALB 16

typedef __attribute__((ext_vector_type(8))) short short8;
typedef __attribute__((ext_vector_type(4))) float f32x4;

static __device__ __forceinline__ unsigned f2u(float f) {
    union { float f; unsigned u; } x; x.f = f; return x.u;
}
static __device__ __forceinline__ unsigned bfpk(float a, float b) {
    return ((f2u(a) + 0x8000u) >> 16) | ((f2u(b) + 0x8000u) & 0xFFFF0000u);
}
static __device__ __forceinline__ unsigned short f2bf(float f) {
    return (unsigned short)((f2u(f) + 0x8000u) >> 16);
}

// In-loop barrier waiting only on LDS ops (lgkmcnt) — global prefetch loads
// stay in flight across it (their waits are dependency-driven at consumption).
static __device__ __forceinline__ void wg_barrier() {
    asm volatile("" ::: "memory");
    __builtin_amdgcn_s_waitcnt(0xC07F);   // vmcnt(63) expcnt(7) lgkmcnt(0)
    __builtin_amdgcn_s_barrier();
    asm volatile("" ::: "memory");
}

static __device__ __forceinline__ bool blk_active(int qb, int kb, int h) {
    return ((qb - kb) < LOCALB) || (((kb + h + 1) & 7) == 0);
}

// LDS row for actual key kk (0..63): key 32c+8q+4e+r -> row 32c+16e+4q+r, so
// S^T C-layout rows (quad*4+r) hold exactly the keys the 16x16x32 B-operand
// layout (k=quad*8+j) wants. Bijection on 0..63.
static __device__ __forceinline__ int krow(int kk) {
    return (kk & 3) | (((kk >> 2) & 1) << 4) | (((kk >> 3) & 3) << 2) | (kk & 32);
}

__global__ __launch_bounds__(256)
void sparse_attn_kernel(const float* __restrict__ Q,
                        const float* __restrict__ K,
                        const float* __restrict__ V,
                        float* __restrict__ O)
{
    // LPT (heavy qb first) + XCD head clustering
    const int id   = blockIdx.x;
    const int h    = (id & 7) * 4 + ((id >> 3) & 3);
    const int qb   = 31 - (id >> 5);

    const int tid  = threadIdx.x;
    const int wave = tid >> 6;
    const int lane = tid & 63;
    const int m16  = lane & 15;
    const int quad = lane >> 4;

    // Aliased LDS: staging (Ks 17408 + Vp 18432 = 35840 B) vs epilogue (33792 B)
    __shared__ __align__(16) char smem[64 * 136 * 2 + 128 * 36 * 4];
    unsigned short (*Ks)[136] = reinterpret_cast<unsigned short(*)[136]>(smem);   // [perm key][d]
    unsigned (*Vp)[36] = reinterpret_cast<unsigned(*)[36]>(smem + 64 * 136 * 2);  // [d][key-pair]

    // ---- Q fragments, scale*log2e folded (B-operand: n=m16->q, k=quad*8+j->d) ----
    const float QSC = 0.08838834764831845f * 1.44269504088896f;
    short8 qf[4];
    {
        const int qrow = qb * 64 + wave * 16 + m16;
        const float* qp = Q + ((size_t)qrow * NH + h) * HD + quad * 8;
        #pragma unroll
        for (int ks = 0; ks < 4; ++ks) {
            const float4 a = *reinterpret_cast<const float4*>(qp + ks * 32);
            const float4 b = *reinterpret_cast<const float4*>(qp + ks * 32 + 4);
            short8 f;
            f[0]=(short)f2bf(a.x*QSC); f[1]=(short)f2bf(a.y*QSC);
            f[2]=(short)f2bf(a.z*QSC); f[3]=(short)f2bf(a.w*QSC);
            f[4]=(short)f2bf(b.x*QSC); f[5]=(short)f2bf(b.y*QSC);
            f[6]=(short)f2bf(b.z*QSC); f[7]=(short)f2bf(b.w*QSC);
            qf[ks] = f;
        }
    }

    // O^T accumulator: lane owns q=m16; acc[dt] rows = d = dt*16+quad*4+reg
    f32x4 acc[8];
    #pragma unroll
    for (int dt = 0; dt < 8; ++dt) { acc[dt][0]=0.f; acc[dt][1]=0.f; acc[dt][2]=0.f; acc[dt][3]=0.f; }
    float mrow = -3.0e38f;
    float lrow = 0.f;

    // staging coordinates
    const int kkey0 = tid >> 5;                 // + it*8
    const int kd4   = (tid & 31) << 2;
    const int vkey0 = wave * 8 + (lane & 7);
    const int vd40  = (lane >> 3) << 2;
    const int vc    = wave * 4 + ((lane & 7) >> 1);

    int kb = 0;
    while (!blk_active(qb, kb, h)) ++kb;        // kb==qb always active

    float4 kreg[8], vreg[8];
    {
        const float* kp = K + (size_t)kb * 262144 + (size_t)kkey0 * 4096 + h * 128 + kd4;
        #pragma unroll
        for (int it = 0; it < 8; ++it)
            kreg[it] = *reinterpret_cast<const float4*>(kp + it * 32768);
        const float* vp = V + (size_t)kb * 262144 + (size_t)vkey0 * 4096 + h * 128 + vd40;
        #pragma unroll
        for (int it = 0; it < 8; ++it)
            vreg[it] = *reinterpret_cast<const float4*>(vp + (it & 1) * 131072 + (it >> 1) * 32);
    }

    while (kb <= qb) {
        int nkb = kb + 1;
        while (nkb <= qb && !blk_active(qb, nkb, h)) ++nkb;

        wg_barrier();   // all waves' LDS reads of prev iteration retired

        // ---- stage K (permuted rows), re-issue K prefetch ----
        #pragma unroll
        for (int it = 0; it < 8; ++it) {
            const float4 kv = kreg[it];
            uint2 pk; pk.x = bfpk(kv.x, kv.y); pk.y = bfpk(kv.z, kv.w);
            *reinterpret_cast<uint2*>(&Ks[krow(it * 8 + kkey0)][kd4]) = pk;
        }
        if (nkb <= qb) {
            const float* kp = K + (size_t)nkb * 262144 + (size_t)kkey0 * 4096 + h * 128 + kd4;
            #pragma unroll
            for (int it = 0; it < 8; ++it)
                kreg[it] = *reinterpret_cast<const float4*>(kp + it * 32768);
        }

        // ---- stage V transposed (pair-packed b32, natural key order) ----
        #pragma unroll
        for (int it = 0; it < 8; ++it) {
            const int d4 = (it >> 1) * 32 + vd40;
            const float4 vv = vreg[it];
            const unsigned p0 = bfpk(vv.x, vv.y);
            const unsigned p1 = bfpk(vv.z, vv.w);
            const unsigned q0 = __shfl_xor(p0, 1);
            const unsigned q1 = __shfl_xor(p1, 1);
            const int c = (it & 1) * 16 + vc;
            if ((lane & 1) == 0) {
                Vp[d4 + 0][c] = (p0 & 0xFFFFu) | (q0 << 16);
                Vp[d4 + 1][c] = (p0 >> 16)     | (q0 & 0xFFFF0000u);
            } else {
                Vp[d4 + 2][c] = (q1 & 0xFFFFu) | (p1 << 16);
                Vp[d4 + 3][c] = (q1 >> 16)     | (p1 & 0xFFFF0000u);
            }
        }
        if (nkb <= qb) {
            const float* vp = V + (size_t)nkb * 262144 + (size_t)vkey0 * 4096 + h * 128 + vd40;
            #pragma unroll
            for (int it = 0; it < 8; ++it)
                vreg[it] = *reinterpret_cast<const float4*>(vp + (it & 1) * 131072 + (it >> 1) * 32);
        }

        wg_barrier();   // staging visible

        // ---- S^T = K Q^T : A = K-frag (m=perm key), B = qf (n=q) ----
        // sc[nt][r] = S^T[actual key = (nt>>1)*32 + quad*8 + (nt&1)*4 + r][q=m16]
        f32x4 sc[4];
        #pragma unroll
        for (int nt = 0; nt < 4; ++nt) {
            f32x4 s = {0.f, 0.f, 0.f, 0.f};
            #pragma unroll
            for (int ks = 0; ks < 4; ++ks) {
                const short8 a = *reinterpret_cast<const short8*>(&Ks[nt * 16 + m16][ks * 32 + quad * 8]);
                s = __builtin_amdgcn_mfma_f32_16x16x32_bf16(a, qf[ks], s, 0, 0, 0);
            }
            sc[nt] = s;
        }

        // ---- diagonal causal mask (actual key index) ----
        if (kb == qb) {
            const int qloc = wave * 16 + m16;
            #pragma unroll
            for (int nt = 0; nt < 4; ++nt) {
                const int kb0 = (nt >> 1) * 32 + quad * 8 + (nt & 1) * 4;
                #pragma unroll
                for (int r = 0; r < 4; ++r) {
                    if (kb0 + r > qloc) sc[nt][r] = -1.0e30f;
                }
            }
        }

        // ---- lane-local online softmax (q = m16 fixed per lane) ----
        float mx = sc[0][0];
        #pragma unroll
        for (int nt = 0; nt < 4; ++nt) {
            #pragma unroll
            for (int r = 0; r < 4; ++r) mx = fmaxf(mx, sc[nt][r]);
        }
        mx = fmaxf(mx, __shfl_xor(mx, 16));
        mx = fmaxf(mx, __shfl_xor(mx, 32));
        const float mnew = fmaxf(mrow, mx);
        const float alpha = __builtin_exp2f(mrow - mnew);
        lrow *= alpha;
        #pragma unroll
        for (int dt = 0; dt < 8; ++dt) {
            acc[dt][0] *= alpha; acc[dt][1] *= alpha;
            acc[dt][2] *= alpha; acc[dt][3] *= alpha;
        }
        float rs = 0.f;
        #pragma unroll
        for (int nt = 0; nt < 4; ++nt) {
            #pragma unroll
            for (int r = 0; r < 4; ++r) {
                const float p = __builtin_exp2f(sc[nt][r] - mnew);
                sc[nt][r] = p;
                rs += p;
            }
        }
        rs += __shfl_xor(rs, 16);
        rs += __shfl_xor(rs, 32);
        lrow += rs;
        mrow = mnew;

        // ---- P^T B-frags (keys 32c+quad*8+j) directly from sc registers ----
        short8 pf[2];
        #pragma unroll
        for (int c = 0; c < 2; ++c) {
            union { unsigned u[4]; short8 s; } cv;
            cv.u[0] = bfpk(sc[2 * c][0],     sc[2 * c][1]);
            cv.u[1] = bfpk(sc[2 * c][2],     sc[2 * c][3]);
            cv.u[2] = bfpk(sc[2 * c + 1][0], sc[2 * c + 1][1]);
            cv.u[3] = bfpk(sc[2 * c + 1][2], sc[2 * c + 1][3]);
            pf[c] = cv.s;
        }

        // ---- O^T += V^T P^T : A = V^T-frag (m=d, k=quad*8+j keys), B = pf ----
        #pragma unroll
        for (int dt = 0; dt < 8; ++dt) {
            #pragma unroll
            for (int c = 0; c < 2; ++c) {
                const short8 a = *reinterpret_cast<const short8*>(
                    &Vp[dt * 16 + m16][c * 16 + quad * 4]);
                acc[dt] = __builtin_amdgcn_mfma_f32_16x16x32_bf16(a, pf[c], acc[dt], 0, 0, 0);
            }
        }

        kb = nkb;
    }

    // ---- epilogue: O^T -> LDS transpose -> coalesced stores ----
    __syncthreads();   // FULL drain before aliasing staging LDS (once/block)
    float* Osf = reinterpret_cast<float*>(smem);   // [64 q][132 d]
    {
        const float inv = 1.0f / lrow;
        const int q = wave * 16 + m16;
        #pragma unroll
        for (int dt = 0; dt < 8; ++dt) {
            f32x4 v = acc[dt];
            v[0] *= inv; v[1] *= inv; v[2] *= inv; v[3] *= inv;
            *reinterpret_cast<f32x4*>(&Osf[q * 132 + dt * 16 + quad * 4]) = v;
        }
    }
    __syncthreads();
    #pragma unroll
    for (int p = 0; p < 2; ++p) {
        const int row = p * 32 + (tid >> 3);
        const int dbase = (tid & 7) * 4;
        #pragma unroll
        for (int i = 0; i < 4; ++i) {
            const int d = i * 32 + dbase;
            const f32x4 v = *reinterpret_cast<const f32x4*>(&Osf[row * 132 + d]);
            *reinterpret_cast<f32x4*>(O + ((size_t)(qb * 64 + row) * NH + h) * HD + d) = v;
        }
    }
}

extern "C" void kernel_launch(void* const* d_in, const int* in_sizes, int n_in,
                              void* d_out, int out_size, void* d_ws, size_t ws_size,
                              hipStream_t stream) {
    const float* q = (const float*)d_in[0];
    const float* k = (const float*)d_in[1];
    const float* v = (const float*)d_in[2];
    float* out = (float*)d_out;
    sparse_attn_kernel<<<dim3(1024), dim3(256), 0, stream>>>(q, k, v, out);
}